// Round 3
// baseline (3580.457 us; speedup 1.0000x reference)
//
#include <hip/hip_runtime.h>
#include <hip/hip_fp16.h>
#include <math.h>

#define B_    8
#define CDIM  256
#define HH    256
#define WW    32
#define PP    8192     // HH*WW
#define HEADS 8
#define FFI   1024

// ---------------- workspace layout (float offsets) ----------------
// Peak d_ws requirement: 17,060,864 floats = 68,243,456 bytes (~65.1 MiB)
// BIG region [0, 16777216): qk fp16 (8,512,8192) -> attn_br fp32 (8,256,8192)
//                           -> h1 slab fp32 (1024,8192) per batch
static const size_t OFF_BIG    = 0;
static const size_t OFF_PM     = 16777216;  // 65536
static const size_t OFF_PR     = 16842752;  // 65536
static const size_t OFF_QPROBE = 16908288;  // 2048
static const size_t OFF_SH     = 16910336;  // 2048
static const size_t OFF_IH     = 16912384;  // 512 ints
static const size_t OFF_IW     = 16912896;  // 512 ints
static const size_t OFF_STM    = 16913408;  // 8192
static const size_t OFF_STR    = 16921600;  // 8192
static const size_t OFF_VSEL   = 16929792;  // 131072
// end: 17060864 floats

// ---------------- channel-LN stats per (b,p) ----------------
__global__ __launch_bounds__(256) void k_lnstats(const float* __restrict__ x,
                                                 float* __restrict__ pm,
                                                 float* __restrict__ pr) {
  int idx = blockIdx.x * 256 + threadIdx.x;      // 65536
  int b = idx >> 13, p = idx & 8191;
  const float* xp = x + (size_t)b * CDIM * PP + p;
  float s = 0.f, s2 = 0.f;
  for (int c = 0; c < CDIM; c++) { float v = xp[(size_t)c * PP]; s += v; s2 += v * v; }
  float m = s * (1.0f / CDIM);
  float var = s2 * (1.0f / CDIM) - m * m;
  pm[idx] = m;
  pr[idx] = rsqrtf(var + 1e-5f);
}

// ---------------- q,k GEMM with fused LN staging + l2norm + fp16 store ----------------
__global__ __launch_bounds__(256) void k_gemm_qk(const float* __restrict__ w_qkv,
                                                 const float* __restrict__ x,
                                                 const float* __restrict__ pm,
                                                 const float* __restrict__ pr,
                                                 const float* __restrict__ g,
                                                 const float* __restrict__ bb,
                                                 __half* __restrict__ qk) {
  __shared__ float As[16][128];
  __shared__ float Bs[16][64];
  int t = threadIdx.x;
  int p0 = blockIdx.x * 64, m0 = blockIdx.y * 128, b = blockIdx.z;
  float acc[8][4];
#pragma unroll
  for (int i = 0; i < 8; i++)
#pragma unroll
    for (int j = 0; j < 4; j++) acc[i][j] = 0.f;
  int ar = t >> 1, ak = (t & 1) * 8;
  int bk = t >> 4, bp4 = (t & 15) * 4;
  int ty = t >> 4, tx = t & 15;
  const float* xb = x + (size_t)b * CDIM * PP;
  const float* pmb = pm + (size_t)b * PP;
  const float* prb = pr + (size_t)b * PP;
  for (int k0 = 0; k0 < 256; k0 += 16) {
    const float* wp = w_qkv + (size_t)(m0 + ar) * 256 + k0 + ak;
    float4 a0 = *(const float4*)wp;
    float4 a1 = *(const float4*)(wp + 4);
    As[ak + 0][ar] = a0.x; As[ak + 1][ar] = a0.y; As[ak + 2][ar] = a0.z; As[ak + 3][ar] = a0.w;
    As[ak + 4][ar] = a1.x; As[ak + 5][ar] = a1.y; As[ak + 6][ar] = a1.z; As[ak + 7][ar] = a1.w;
    int c = k0 + bk;
    float4 xv = *(const float4*)(xb + (size_t)c * PP + p0 + bp4);
    float4 pmv = *(const float4*)(pmb + p0 + bp4);
    float4 prv = *(const float4*)(prb + p0 + bp4);
    float gc = g[c], bc = bb[c];
    Bs[bk][bp4 + 0] = (xv.x - pmv.x) * prv.x * gc + bc;
    Bs[bk][bp4 + 1] = (xv.y - pmv.y) * prv.y * gc + bc;
    Bs[bk][bp4 + 2] = (xv.z - pmv.z) * prv.z * gc + bc;
    Bs[bk][bp4 + 3] = (xv.w - pmv.w) * prv.w * gc + bc;
    __syncthreads();
#pragma unroll
    for (int kk = 0; kk < 16; kk++) {
      float4 af0 = *(const float4*)&As[kk][ty * 8];
      float4 af1 = *(const float4*)&As[kk][ty * 8 + 4];
      float4 bf  = *(const float4*)&Bs[kk][tx * 4];
      float a[8] = {af0.x, af0.y, af0.z, af0.w, af1.x, af1.y, af1.z, af1.w};
      float bq[4] = {bf.x, bf.y, bf.z, bf.w};
#pragma unroll
      for (int i = 0; i < 8; i++)
#pragma unroll
        for (int j = 0; j < 4; j++) acc[i][j] += a[i] * bq[j];
    }
    __syncthreads();
  }
  // l2-normalize over groups of 32 p's (tx groups of 8, lanes differ in bits 0-2)
#pragma unroll
  for (int i = 0; i < 8; i++) {
    float s = acc[i][0] * acc[i][0] + acc[i][1] * acc[i][1]
            + acc[i][2] * acc[i][2] + acc[i][3] * acc[i][3];
    s += __shfl_xor(s, 1);
    s += __shfl_xor(s, 2);
    s += __shfl_xor(s, 4);
    float inv = 1.0f / fmaxf(sqrtf(s), 1e-12f);
    int m = m0 + ty * 8 + i;
    size_t off = ((size_t)b * 512 + m) * PP + p0 + tx * 4;
    __half2* dst = (__half2*)(qk + off);
    dst[0] = __halves2half2(__float2half(acc[i][0] * inv), __float2half(acc[i][1] * inv));
    dst[1] = __halves2half2(__float2half(acc[i][2] * inv), __float2half(acc[i][3] * inv));
  }
}

// ---------------- q_probe + sh scores (fp16 qk) ----------------
__global__ __launch_bounds__(256) void k_probe(const __half* __restrict__ qk,
                                               float* __restrict__ qprobe,
                                               float* __restrict__ sh) {
  __shared__ float part[8][32];
  __shared__ float qp[32];
  int bh = blockIdx.x, b = bh >> 3, hd = bh & 7;
  int t = threadIdx.x, w = t & 31, pt = t >> 5;
  const __half* qb = qk + ((size_t)(b * 512 + hd * 32)) * PP;
  float s = 0.f;
  for (int d = 0; d < 32; d++) {
    const __half* qd = qb + (size_t)d * PP + w;
    for (int h = pt * 32; h < pt * 32 + 32; h++) s += __half2float(qd[h * 32]);
  }
  part[pt][w] = s;
  __syncthreads();
  if (t < 32) {
    float acc = 0.f;
    for (int i = 0; i < 8; i++) acc += part[i][w];
    qp[w] = acc;
    qprobe[bh * 32 + w] = acc;
  }
  __syncthreads();
  const __half* kb = qk + ((size_t)(b * 512 + 256 + hd * 32)) * PP;
  for (int dd = 0; dd < 4; dd++) {
    int d = pt * 4 + dd;
    const __half* kd = kb + (size_t)d * PP + w;
    float ks = 0.f;
    for (int h = 0; h < 256; h++) ks += __half2float(kd[h * 32]);
    float prod = qp[w] * ks;
#pragma unroll
    for (int off = 16; off; off >>= 1) prod += __shfl_xor(prod, off);
    if (w == 0) sh[bh * 32 + d] = prod;
  }
}

// ---------------- top-8 of 32 (dim_head axis) ----------------
__global__ __launch_bounds__(64) void k_topk_h(const float* __restrict__ sh, int* __restrict__ ih) {
  int bh = blockIdx.x;
  if (threadIdx.x != 0) return;
  float v[32];
#pragma unroll
  for (int i = 0; i < 32; i++) v[i] = sh[bh * 32 + i];
  for (int s = 0; s < 8; s++) {
    int bi = 0; float bv = v[0];
#pragma unroll
    for (int i = 1; i < 32; i++) { if (v[i] > bv) { bv = v[i]; bi = i; } }
    ih[bh * 8 + s] = bi;
    v[bi] = -3.4e38f;
  }
}

// ---------------- sw scores + top-8 of 256 (spatial H axis) ----------------
__global__ __launch_bounds__(256) void k_sw_topk(const __half* __restrict__ qk,
                                                 const float* __restrict__ qprobe,
                                                 const int* __restrict__ ih,
                                                 int* __restrict__ iw) {
  __shared__ float qp[32];
  __shared__ float sw[256];
  __shared__ int ihs[8];
  int bh = blockIdx.x, b = bh >> 3, hd = bh & 7;
  int t = threadIdx.x;
  if (t < 32) qp[t] = qprobe[bh * 32 + t];
  if (t < 8) ihs[t] = ih[bh * 8 + t];
  __syncthreads();
  const __half* kb = qk + ((size_t)(b * 512 + 256 + hd * 32)) * PP;
  float s = 0.f;
  for (int a = 0; a < 8; a++) {
    const __half* kd = kb + (size_t)ihs[a] * PP + t * 32;
#pragma unroll
    for (int w = 0; w < 32; w++) s += qp[w] * __half2float(kd[w]);
  }
  sw[t] = s;
  __syncthreads();
  if (t == 0) {
    for (int sel = 0; sel < 8; sel++) {
      int bi = 0; float bv = sw[0];
      for (int i = 1; i < 256; i++) { if (sw[i] > bv) { bv = sw[i]; bi = i; } }
      iw[bh * 8 + sel] = bi;
      sw[bi] = -3.4e38f;
    }
  }
}

// ---------------- recompute v at the 64 selected positions per bh ----------------
__global__ __launch_bounds__(256) void k_vsel(const float* __restrict__ w_qkv,
                                              const float* __restrict__ x,
                                              const float* __restrict__ pm,
                                              const float* __restrict__ pr,
                                              const float* __restrict__ g,
                                              const float* __restrict__ bb,
                                              const int* __restrict__ ih,
                                              const int* __restrict__ iw,
                                              float* __restrict__ vsel) {
  __shared__ int ihs[8], iws[8];
  int bh = blockIdx.x, b = bh >> 3, hd = bh & 7;
  int t = threadIdx.x;
  if (t < 8) { ihs[t] = ih[bh * 8 + t]; iws[t] = iw[bh * 8 + t]; }
  __syncthreads();
  const float* xb = x + (size_t)b * CDIM * PP;
  for (int o = t; o < 2048; o += 256) {
    int j = o >> 5, w = o & 31;
    int a = j >> 3, bi = j & 7;
    int d = ihs[a], hsp = iws[bi];
    int p = hsp * 32 + w;
    const float* wv = w_qkv + (size_t)(512 + hd * 32 + d) * 256;
    float pmv = pm[(size_t)b * PP + p], prv = pr[(size_t)b * PP + p];
    float s = 0.f;
    for (int c = 0; c < 256; c++)
      s += wv[c] * ((xb[(size_t)c * PP + p] - pmv) * prv * g[c] + bb[c]);
    vsel[((size_t)bh * 64 + j) * 32 + w] = s;
  }
}

// ---------------- attention ----------------
__global__ __launch_bounds__(256) void k_attn(const __half* __restrict__ qk,
                                              const float* __restrict__ vsel,
                                              const int* __restrict__ ih,
                                              const int* __restrict__ iw,
                                              float* __restrict__ o_r) {
  __shared__ float ks[64][32];
  __shared__ float vs[64][32];
  __shared__ int ihs[8], iws[8];
  int bh = blockIdx.y, b = bh >> 3, hd = bh & 7;
  int t = threadIdx.x;
  if (t < 8) { ihs[t] = ih[bh * 8 + t]; iws[t] = iw[bh * 8 + t]; }
  __syncthreads();
  const __half* kb = qk + ((size_t)(b * 512 + 256 + hd * 32)) * PP;
  for (int idx = t; idx < 2048; idx += 256) {
    int j = idx >> 5, w = idx & 31;
    int a = j >> 3, bi = j & 7;
    ks[j][w] = __half2float(kb[(size_t)ihs[a] * PP + iws[bi] * 32 + w]);
    vs[j][w] = vsel[((size_t)bh * 64 + j) * 32 + w];
  }
  __syncthreads();
  int i = blockIdx.x * 256 + t;          // row in [0,8192)
  int dq = i >> 8, hsp = i & 255;
  const __half* qrow = qk + ((size_t)(b * 512 + hd * 32 + dq)) * PP + hsp * 32;
  float q[32];
#pragma unroll
  for (int w = 0; w < 32; w++) q[w] = __half2float(qrow[w]);
  float mx = -3.4e38f;
  for (int j = 0; j < 64; j++) {
    float d = 0.f;
#pragma unroll
    for (int w = 0; w < 32; w++) d += q[w] * ks[j][w];
    mx = fmaxf(mx, d);
  }
  float o[32];
#pragma unroll
  for (int w = 0; w < 32; w++) o[w] = 0.f;
  float l = 0.f;
  for (int j = 0; j < 64; j++) {
    float d = 0.f;
#pragma unroll
    for (int w = 0; w < 32; w++) d += q[w] * ks[j][w];
    float e = __expf(d - mx);
    l += e;
#pragma unroll
    for (int w = 0; w < 32; w++) o[w] += e * vs[j][w];
  }
  float inv = 1.0f / l;
  float* op = o_r + ((size_t)(b * 256 + hd * 32)) * PP + i;
#pragma unroll
  for (int dd = 0; dd < 32; dd++) op[(size_t)dd * PP] = o[dd] * inv;
}

// ---------------- generic fp32 tiled GEMM (batch via grid.z and strides) ----------------
__global__ __launch_bounds__(256) void k_gemm(const float* __restrict__ Wt, int ldw,
                                              const float* __restrict__ In, size_t inStride,
                                              float* __restrict__ Out, size_t outStride,
                                              const float* __restrict__ bias,
                                              int M, int K) {
  __shared__ float As[16][128];
  __shared__ float Bs[16][64];
  int t = threadIdx.x;
  int p0 = blockIdx.x * 64, m0 = blockIdx.y * 128, z = blockIdx.z;
  const float* inB = In + (size_t)z * inStride;
  float acc[8][4];
#pragma unroll
  for (int i = 0; i < 8; i++)
#pragma unroll
    for (int j = 0; j < 4; j++) acc[i][j] = 0.f;
  int ar = t >> 1, ak = (t & 1) * 8;
  int bk = t >> 4, bp4 = (t & 15) * 4;
  int ty = t >> 4, tx = t & 15;
  for (int k0 = 0; k0 < K; k0 += 16) {
    const float* wp = Wt + (size_t)(m0 + ar) * ldw + k0 + ak;
    float4 a0 = *(const float4*)wp;
    float4 a1 = *(const float4*)(wp + 4);
    As[ak + 0][ar] = a0.x; As[ak + 1][ar] = a0.y; As[ak + 2][ar] = a0.z; As[ak + 3][ar] = a0.w;
    As[ak + 4][ar] = a1.x; As[ak + 5][ar] = a1.y; As[ak + 6][ar] = a1.z; As[ak + 7][ar] = a1.w;
    float4 bv = *(const float4*)(inB + (size_t)(k0 + bk) * PP + p0 + bp4);
    *(float4*)&Bs[bk][bp4] = bv;
    __syncthreads();
#pragma unroll
    for (int kk = 0; kk < 16; kk++) {
      float4 af0 = *(const float4*)&As[kk][ty * 8];
      float4 af1 = *(const float4*)&As[kk][ty * 8 + 4];
      float4 bf  = *(const float4*)&Bs[kk][tx * 4];
      float a[8] = {af0.x, af0.y, af0.z, af0.w, af1.x, af1.y, af1.z, af1.w};
      float bq[4] = {bf.x, bf.y, bf.z, bf.w};
#pragma unroll
      for (int i = 0; i < 8; i++)
#pragma unroll
        for (int j = 0; j < 4; j++) acc[i][j] += a[i] * bq[j];
    }
    __syncthreads();
  }
#pragma unroll
  for (int i = 0; i < 8; i++) {
    int m = m0 + ty * 8 + i;
    float bs = bias ? bias[m] : 0.0f;
    size_t off = (size_t)z * outStride + (size_t)m * PP + p0 + tx * 4;
    float4 r;
    r.x = acc[i][0] + bs; r.y = acc[i][1] + bs; r.z = acc[i][2] + bs; r.w = acc[i][3] + bs;
    *(float4*)(Out + off) = r;
  }
}

// ---------------- comb GEMM: K=512, second half stages dwconv(x) on the fly ----------------
__global__ __launch_bounds__(256) void k_gemm_comb(const float* __restrict__ Wt,   // (256,512)
                                                   const float* __restrict__ attn_br,
                                                   const float* __restrict__ x,
                                                   const float* __restrict__ wdw,
                                                   const float* __restrict__ bdw,
                                                   const float* __restrict__ bias,
                                                   float* __restrict__ Out) {
  __shared__ float As[16][128];
  __shared__ float Bs[16][64];
  int t = threadIdx.x;
  int p0 = blockIdx.x * 64, m0 = blockIdx.y * 128, b = blockIdx.z;
  float acc[8][4];
#pragma unroll
  for (int i = 0; i < 8; i++)
#pragma unroll
    for (int j = 0; j < 4; j++) acc[i][j] = 0.f;
  int ar = t >> 1, ak = (t & 1) * 8;
  int bk = t >> 4, bp4 = (t & 15) * 4;
  int ty = t >> 4, tx = t & 15;
  int p = p0 + bp4;
  int x0 = p >> 5, y0 = p & 31;
  const float* aB = attn_br + (size_t)b * CDIM * PP;
  const float* xB = x + (size_t)b * CDIM * PP;
  for (int k0 = 0; k0 < 512; k0 += 16) {
    const float* wp = Wt + (size_t)(m0 + ar) * 512 + k0 + ak;
    float4 a0 = *(const float4*)wp;
    float4 a1 = *(const float4*)(wp + 4);
    As[ak + 0][ar] = a0.x; As[ak + 1][ar] = a0.y; As[ak + 2][ar] = a0.z; As[ak + 3][ar] = a0.w;
    As[ak + 4][ar] = a1.x; As[ak + 5][ar] = a1.y; As[ak + 6][ar] = a1.z; As[ak + 7][ar] = a1.w;
    int c = k0 + bk;
    if (c < 256) {
      float4 bv = *(const float4*)(aB + (size_t)c * PP + p0 + bp4);
      *(float4*)&Bs[bk][bp4] = bv;
    } else {
      int cc = c - 256;
      const float* hp = xB + (size_t)cc * PP;
      float nb[3][6];
#pragma unroll
      for (int i = 0; i < 3; i++) {
        int xx = x0 - 1 + i;
        bool vx = (xx >= 0) && (xx < HH);
#pragma unroll
        for (int j = 0; j < 6; j++) {
          int yy = y0 - 1 + j;
          nb[i][j] = (vx && yy >= 0 && yy < WW) ? hp[xx * 32 + yy] : 0.f;
        }
      }
      const float* wf = wdw + cc * 9;
      float bd = bdw[cc];
#pragma unroll
      for (int e = 0; e < 4; e++) {
        float d = bd;
#pragma unroll
        for (int i = 0; i < 3; i++)
#pragma unroll
          for (int j = 0; j < 3; j++) d += wf[i * 3 + j] * nb[i][e + j];
        Bs[bk][bp4 + e] = d;
      }
    }
    __syncthreads();
#pragma unroll
    for (int kk = 0; kk < 16; kk++) {
      float4 af0 = *(const float4*)&As[kk][ty * 8];
      float4 af1 = *(const float4*)&As[kk][ty * 8 + 4];
      float4 bf  = *(const float4*)&Bs[kk][tx * 4];
      float a[8] = {af0.x, af0.y, af0.z, af0.w, af1.x, af1.y, af1.z, af1.w};
      float bq[4] = {bf.x, bf.y, bf.z, bf.w};
#pragma unroll
      for (int i = 0; i < 8; i++)
#pragma unroll
        for (int j = 0; j < 4; j++) acc[i][j] += a[i] * bq[j];
    }
    __syncthreads();
  }
#pragma unroll
  for (int i = 0; i < 8; i++) {
    int m = m0 + ty * 8 + i;
    float bs = bias[m];
    size_t off = ((size_t)b * CDIM + m) * PP + p0 + tx * 4;
    float4 rv = *(const float4*)(xB + (size_t)m * PP + p0 + tx * 4);   // residual +x
    float4 r;
    r.x = acc[i][0] + bs + rv.x; r.y = acc[i][1] + bs + rv.y;
    r.z = acc[i][2] + bs + rv.z; r.w = acc[i][3] + bs + rv.w;
    *(float4*)(Out + off) = r;
  }
}

// ---------------- ff2 GEMM (per-b) with fused h2 = h1 + gelu(inorm(dwconv(h1))) ----------------
__global__ __launch_bounds__(256) void k_gemm_ff2(const float* __restrict__ Wt,   // (256,1024)
                                                  const float* __restrict__ h1,  // (1024,8192)
                                                  const float* __restrict__ wdw,
                                                  const float* __restrict__ bdw,
                                                  const float* __restrict__ stm,
                                                  const float* __restrict__ str,
                                                  float* __restrict__ Out,       // (256,8192)
                                                  const float* __restrict__ bias) {
  __shared__ float As[16][128];
  __shared__ float Bs[16][64];
  int t = threadIdx.x;
  int p0 = blockIdx.x * 64, m0 = blockIdx.y * 128;
  float acc[8][4];
#pragma unroll
  for (int i = 0; i < 8; i++)
#pragma unroll
    for (int j = 0; j < 4; j++) acc[i][j] = 0.f;
  int ar = t >> 1, ak = (t & 1) * 8;
  int bk = t >> 4, bp4 = (t & 15) * 4;
  int ty = t >> 4, tx = t & 15;
  int p = p0 + bp4;
  int x0 = p >> 5, y0 = p & 31;
  for (int k0 = 0; k0 < FFI; k0 += 16) {
    const float* wp = Wt + (size_t)(m0 + ar) * FFI + k0 + ak;
    float4 a0 = *(const float4*)wp;
    float4 a1 = *(const float4*)(wp + 4);
    As[ak + 0][ar] = a0.x; As[ak + 1][ar] = a0.y; As[ak + 2][ar] = a0.z; As[ak + 3][ar] = a0.w;
    As[ak + 4][ar] = a1.x; As[ak + 5][ar] = a1.y; As[ak + 6][ar] = a1.z; As[ak + 7][ar] = a1.w;
    int c = k0 + bk;
    const float* hp = h1 + (size_t)c * PP;
    float nb[3][6];
#pragma unroll
    for (int i = 0; i < 3; i++) {
      int xx = x0 - 1 + i;
      bool vx = (xx >= 0) && (xx < HH);
#pragma unroll
      for (int j = 0; j < 6; j++) {
        int yy = y0 - 1 + j;
        nb[i][j] = (vx && yy >= 0 && yy < WW) ? hp[xx * 32 + yy] : 0.f;
      }
    }
    float m = stm[c], r = str[c];
    const float* wf = wdw + c * 9;
    float bd = bdw[c];
#pragma unroll
    for (int e = 0; e < 4; e++) {
      float d = bd;
#pragma unroll
      for (int i = 0; i < 3; i++)
#pragma unroll
        for (int j = 0; j < 3; j++) d += wf[i * 3 + j] * nb[i][e + j];
      float nv = (d - m) * r;
      float ge = 0.5f * nv * (1.0f + erff(nv * 0.70710678118f));
      Bs[bk][bp4 + e] = nb[1][e + 1] + ge;
    }
    __syncthreads();
#pragma unroll
    for (int kk = 0; kk < 16; kk++) {
      float4 af0 = *(const float4*)&As[kk][ty * 8];
      float4 af1 = *(const float4*)&As[kk][ty * 8 + 4];
      float4 bf  = *(const float4*)&Bs[kk][tx * 4];
      float a[8] = {af0.x, af0.y, af0.z, af0.w, af1.x, af1.y, af1.z, af1.w};
      float bq[4] = {bf.x, bf.y, bf.z, bf.w};
#pragma unroll
      for (int i = 0; i < 8; i++)
#pragma unroll
        for (int j = 0; j < 4; j++) acc[i][j] += a[i] * bq[j];
    }
    __syncthreads();
  }
#pragma unroll
  for (int i = 0; i < 8; i++) {
    int m = m0 + ty * 8 + i;
    float bs = bias[m];
    size_t off = (size_t)m * PP + p0 + tx * 4;
    float4 r;
    r.x = acc[i][0] + bs; r.y = acc[i][1] + bs; r.z = acc[i][2] + bs; r.w = acc[i][3] + bs;
    *(float4*)(Out + off) = r;
  }
}

// ---------------- instance-norm stats per row of 8192 ----------------
__global__ __launch_bounds__(256) void k_istats(const float* __restrict__ in,
                                                float* __restrict__ stm,
                                                float* __restrict__ str) {
  __shared__ float ss[256], ss2[256];
  int row = blockIdx.x, t = threadIdx.x;
  const float* p = in + (size_t)row * PP;
  float s = 0.f, s2 = 0.f;
  for (int i = t; i < PP; i += 256) { float v = p[i]; s += v; s2 += v * v; }
  ss[t] = s; ss2[t] = s2;
  __syncthreads();
  for (int off = 128; off; off >>= 1) {
    if (t < off) { ss[t] += ss[t + off]; ss2[t] += ss2[t + off]; }
    __syncthreads();
  }
  if (t == 0) {
    float m = ss[0] * (1.0f / PP);
    float var = ss2[0] * (1.0f / PP) - m * m;
    stm[row] = m;
    str[row] = rsqrtf(var + 1e-5f);
  }
}

// ---------------- dw-conv stats on the fly (per-b slab) ----------------
__global__ __launch_bounds__(256) void k_ffdw_stats(const float* __restrict__ h1,
                                                    const float* __restrict__ wdw,
                                                    const float* __restrict__ bdw,
                                                    float* __restrict__ stm,
                                                    float* __restrict__ str) {
  __shared__ float ss[256], ss2[256];
  int c = blockIdx.x;                 // [0,1024)
  const float* hp = h1 + (size_t)c * PP;
  const float* wf = wdw + c * 9;
  float bd = bdw[c];
  int t = threadIdx.x;
  float s = 0.f, s2 = 0.f;
  for (int p = t; p < PP; p += 256) {
    int x0 = p >> 5, y0 = p & 31;
    float d = bd;
#pragma unroll
    for (int i = 0; i < 3; i++) {
      int xx = x0 + i - 1;
      if (xx < 0 || xx >= HH) continue;
#pragma unroll
      for (int j = 0; j < 3; j++) {
        int yy = y0 + j - 1;
        if (yy < 0 || yy >= WW) continue;
        d += wf[i * 3 + j] * hp[xx * 32 + yy];
      }
    }
    s += d; s2 += d * d;
  }
  ss[t] = s; ss2[t] = s2;
  __syncthreads();
  for (int off = 128; off; off >>= 1) {
    if (t < off) { ss[t] += ss[t + off]; ss2[t] += ss2[t + off]; }
    __syncthreads();
  }
  if (t == 0) {
    float m = ss[0] * (1.0f / PP);
    float var = ss2[0] * (1.0f / PP) - m * m;
    stm[c] = m;
    str[c] = rsqrtf(var + 1e-5f);
  }
}

// ---------------- apply inorm (+gelu) ----------------
__global__ __launch_bounds__(256) void k_napply(const float* __restrict__ in,
                                                const float* __restrict__ stm,
                                                const float* __restrict__ str,
                                                float* __restrict__ out, int mode) {
  size_t idx = (size_t)blockIdx.x * 256 + threadIdx.x;
  int row = (int)(idx >> 13);
  float v = (in[idx] - stm[row]) * str[row];
  if (mode >= 1) v = 0.5f * v * (1.0f + erff(v * 0.70710678118f));
  out[idx] = v;
}

extern "C" void kernel_launch(void* const* d_in, const int* in_sizes, int n_in,
                              void* d_out, int out_size, void* d_ws, size_t ws_size,
                              hipStream_t stream) {
  const float* x      = (const float*)d_in[0];
  const float* cln_g  = (const float*)d_in[1];
  const float* cln_b  = (const float*)d_in[2];
  const float* w_qkv  = (const float*)d_in[3];
  const float* w_out  = (const float*)d_in[4];
  const float* b_out  = (const float*)d_in[5];
  const float* w_dw   = (const float*)d_in[6];
  const float* b_dw   = (const float*)d_in[7];
  const float* w_comb = (const float*)d_in[8];
  const float* b_comb = (const float*)d_in[9];
  const float* w_ff1  = (const float*)d_in[10];
  const float* b_ff1  = (const float*)d_in[11];
  const float* w_ffdw = (const float*)d_in[12];
  const float* b_ffdw = (const float*)d_in[13];
  const float* w_ff2  = (const float*)d_in[14];
  const float* b_ff2  = (const float*)d_in[15];
  float* out = (float*)d_out;

  float* ws = (float*)d_ws;
  __half* qk     = (__half*)(ws + OFF_BIG);   // fp16 (8,512,8192) = 64MB
  float* attn_br = ws + OFF_BIG;              // fp32 (8,256,8192), after qk dead
  float* slab    = ws + OFF_BIG;              // fp32 (1024,8192) per-b, after attn_br dead
  float* pm      = ws + OFF_PM;
  float* pr      = ws + OFF_PR;
  float* qprobe  = ws + OFF_QPROBE;
  float* sh      = ws + OFF_SH;
  int*   ih      = (int*)(ws + OFF_IH);
  int*   iw      = (int*)(ws + OFF_IW);
  float* stm     = ws + OFF_STM;
  float* str     = ws + OFF_STR;
  float* vsel    = ws + OFF_VSEL;
  float* o_r     = out;                        // d_out as o_r, then comb, then final

  // 1. LN stats
  hipLaunchKernelGGL(k_lnstats, dim3(256), dim3(256), 0, stream, x, pm, pr);
  // 2. q,k GEMM (fused LN staging, l2norm, fp16 store)
  hipLaunchKernelGGL(k_gemm_qk, dim3(128, 4, 8), dim3(256), 0, stream,
                     w_qkv, x, pm, pr, cln_g, cln_b, qk);
  // 3-5. probe + top-k selections
  hipLaunchKernelGGL(k_probe, dim3(64), dim3(256), 0, stream, qk, qprobe, sh);
  hipLaunchKernelGGL(k_topk_h, dim3(64), dim3(64), 0, stream, sh, ih);
  hipLaunchKernelGGL(k_sw_topk, dim3(64), dim3(256), 0, stream, qk, qprobe, ih, iw);
  // 6. v at selected positions
  hipLaunchKernelGGL(k_vsel, dim3(64), dim3(256), 0, stream,
                     w_qkv, x, pm, pr, cln_g, cln_b, ih, iw, vsel);
  // 7. attention -> o_r (d_out)
  hipLaunchKernelGGL(k_attn, dim3(32, 64), dim3(256), 0, stream, qk, vsel, ih, iw, o_r);
  // 8. attn_branch GEMM -> ws BIG (qk dead)
  hipLaunchKernelGGL(k_gemm, dim3(128, 2, 8), dim3(256), 0, stream,
                     w_out, 256, o_r, (size_t)CDIM * PP, attn_br, (size_t)CDIM * PP,
                     b_out, 256, 256);
  // 9. comb GEMM (fused dw-conv staging, +x residual) -> d_out (o_r dead)
  hipLaunchKernelGGL(k_gemm_comb, dim3(128, 2, 8), dim3(256), 0, stream,
                     w_comb, attn_br, x, w_dw, b_dw, b_comb, out);
  // 10. FF chain per batch (slab overlays attn_br region, 32MB)
  for (int b = 0; b < 8; b++) {
    const float* combB = out + (size_t)b * CDIM * PP;
    float* outB = out + (size_t)b * CDIM * PP;
    hipLaunchKernelGGL(k_gemm, dim3(128, 8, 1), dim3(256), 0, stream,
                       w_ff1, 256, combB, (size_t)0, slab, (size_t)0, b_ff1, 1024, 256);
    hipLaunchKernelGGL(k_istats, dim3(1024), dim3(256), 0, stream, slab, stm, str);
    hipLaunchKernelGGL(k_napply, dim3(32768), dim3(256), 0, stream, slab, stm, str, slab, 1);
    hipLaunchKernelGGL(k_ffdw_stats, dim3(1024), dim3(256), 0, stream,
                       slab, w_ffdw, b_ffdw, stm, str);
    hipLaunchKernelGGL(k_gemm_ff2, dim3(128, 2, 1), dim3(256), 0, stream,
                       w_ff2, slab, w_ffdw, b_ffdw, stm, str, outB, b_ff2);
  }
  // 11. final inorm in place on d_out
  hipLaunchKernelGGL(k_istats, dim3(2048), dim3(256), 0, stream, out, stm, str);
  hipLaunchKernelGGL(k_napply, dim3(65536), dim3(256), 0, stream, out, stm, str, out, 0);
}

// Round 4
// 1719.854 us; speedup vs baseline: 2.0818x; 2.0818x over previous
//
#include <hip/hip_runtime.h>
#include <hip/hip_fp16.h>
#include <math.h>

#define B_    8
#define CDIM  256
#define HH    256
#define WW    32
#define PP    8192
#define HEADS 8
#define FFI   1024

typedef _Float16 f16;
typedef _Float16 half8 __attribute__((ext_vector_type(8)));
typedef _Float16 f16x2v __attribute__((ext_vector_type(2)));
typedef float f32x4 __attribute__((ext_vector_type(4)));

// ---------------- workspace layout (float offsets), same 65.1 MiB footprint as round 3 ----------------
static const size_t OFF_PM     = 16777216;
static const size_t OFF_PR     = 16842752;
static const size_t OFF_QPROBE = 16908288;
static const size_t OFF_SH     = 16910336;
static const size_t OFF_IH     = 16912384;
static const size_t OFF_IW     = 16912896;
static const size_t OFF_STM    = 16913408;
static const size_t OFF_STR    = 16921600;
static const size_t OFF_VSEL   = 16929792;
// end: 17060864 floats

// ---------------- channel-LN stats per (b,p) ----------------
__global__ __launch_bounds__(256) void k_lnstats(const float* __restrict__ x,
                                                 float* __restrict__ pm,
                                                 float* __restrict__ pr) {
  int idx = blockIdx.x * 256 + threadIdx.x;
  int b = idx >> 13;
  const float* xp = x + (size_t)b * CDIM * PP + (idx & 8191);
  float s = 0.f, s2 = 0.f;
  for (int c = 0; c < CDIM; c++) { float v = xp[(size_t)c * PP]; s += v; s2 += v * v; }
  float m = s * (1.0f / CDIM);
  float var = s2 * (1.0f / CDIM) - m * m;
  pm[idx] = m;
  pr[idx] = rsqrtf(var + 1e-5f);
}

// ---------------- xn fp16 = LN(x) ----------------
__global__ __launch_bounds__(256) void k_ln_xnf16(const float* __restrict__ x,
                                                  const float* __restrict__ pm,
                                                  const float* __restrict__ pr,
                                                  const float* __restrict__ g,
                                                  const float* __restrict__ bb,
                                                  f16* __restrict__ xn) {
  int blk = blockIdx.x;                 // 8192
  int row = blk >> 2, qq = blk & 3;     // row = b*256+c
  int p = qq * 2048 + threadIdx.x * 8;
  int b = row >> 8, c = row & 255;
  const float* xp = x + (size_t)row * PP + p;
  const float* pmp = pm + (size_t)b * PP + p;
  const float* prp = pr + (size_t)b * PP + p;
  float gc = g[c], bc = bb[c];
  half8 h;
#pragma unroll
  for (int e = 0; e < 8; e++) h[e] = (f16)((xp[e] - pmp[e]) * prp[e] * gc + bc);
  *(half8*)(xn + (size_t)row * PP + p) = h;
}

// ================= MFMA fp16 GEMM (128x128 tile, BK=32) =================
// Out[z][m][p] = sum_k W[m*K+k] * In[z*inZ + k*PP + p]  (+bias[m]) (+resid)
#define MF_STAGE                                                                   \
  int t = threadIdx.x;                                                             \
  int p0 = blockIdx.x * 128, m0 = blockIdx.y * 128, z = blockIdx.z;                \
  int lane = t & 63, wave = t >> 6;                                                \
  int wm = (wave >> 1) * 64, wp = (wave & 1) * 64;                                 \
  int col = lane & 15, quad = lane >> 4;                                           \
  f32x4 acc[4][4];                                                                 \
  _Pragma("unroll") for (int i = 0; i < 4; i++)                                    \
  _Pragma("unroll") for (int j = 0; j < 4; j++)                                    \
      acc[i][j] = (f32x4){0.f, 0.f, 0.f, 0.f};                                     \
  int am = t >> 1, ak = (t & 1) * 16;                                              \
  int bp = (t & 15) * 8, bk = (t >> 4) * 2;                                        \
  int erot = t & 7;                                                                \
  for (int k0 = 0; k0 < K; k0 += 32) {                                             \
    const float* wr = W + (size_t)(m0 + am) * K + k0 + ak;                         \
    float4 w0 = *(const float4*)wr;                                                \
    float4 w1 = *(const float4*)(wr + 4);                                          \
    float4 w2 = *(const float4*)(wr + 8);                                          \
    float4 w3 = *(const float4*)(wr + 12);                                         \
    half8 h0, h1;                                                                  \
    h0[0]=(f16)w0.x; h0[1]=(f16)w0.y; h0[2]=(f16)w0.z; h0[3]=(f16)w0.w;            \
    h0[4]=(f16)w1.x; h0[5]=(f16)w1.y; h0[6]=(f16)w1.z; h0[7]=(f16)w1.w;            \
    h1[0]=(f16)w2.x; h1[1]=(f16)w2.y; h1[2]=(f16)w2.z; h1[3]=(f16)w2.w;            \
    h1[4]=(f16)w3.x; h1[5]=(f16)w3.y; h1[6]=(f16)w3.z; h1[7]=(f16)w3.w;            \
    *(half8*)&As[am][ak] = h0;                                                     \
    *(half8*)&As[am][ak + 8] = h1;                                                 \
    half8 r0 = *(const half8*)(inB + (size_t)(k0 + bk) * PP + p0 + bp);            \
    half8 r1 = *(const half8*)(inB + (size_t)(k0 + bk + 1) * PP + p0 + bp);        \
    _Pragma("unroll") for (int e0 = 0; e0 < 8; e0++) {                             \
      int e = (e0 + erot) & 7;                                                     \
      f16x2v pr2; pr2[0] = r0[e]; pr2[1] = r1[e];                                  \
      *(f16x2v*)&Bs[bp + e][bk] = pr2;                                             \
    }                                                                              \
    __syncthreads();                                                               \
    half8 af[4], bf[4];                                                            \
    _Pragma("unroll") for (int i = 0; i < 4; i++)                                  \
      af[i] = *(const half8*)&As[wm + i * 16 + col][quad * 8];                     \
    _Pragma("unroll") for (int j = 0; j < 4; j++)                                  \
      bf[j] = *(const half8*)&Bs[wp + j * 16 + col][quad * 8];                     \
    _Pragma("unroll") for (int i = 0; i < 4; i++)                                  \
    _Pragma("unroll") for (int j = 0; j < 4; j++)                                  \
        acc[i][j] = __builtin_amdgcn_mfma_f32_16x16x32_f16(af[i], bf[j],           \
                                                           acc[i][j], 0, 0, 0);    \
    __syncthreads();                                                               \
  }

__global__ __launch_bounds__(256) void k_mf(const float* __restrict__ W,
                                            const f16* __restrict__ In, size_t inZ,
                                            f16* __restrict__ OutH,
                                            float* __restrict__ OutF, size_t outZ,
                                            const float* __restrict__ bias,
                                            const float* __restrict__ resid, size_t residZ,
                                            int K) {
  __shared__ f16 As[128][40];
  __shared__ f16 Bs[128][40];
  const f16* inB = In + (size_t)blockIdx.z * inZ;
  MF_STAGE
#pragma unroll
  for (int i = 0; i < 4; i++) {
    int mb = m0 + wm + i * 16 + quad * 4;
#pragma unroll
    for (int r = 0; r < 4; r++) {
      int m = mb + r;
      float bs = bias ? bias[m] : 0.f;
#pragma unroll
      for (int j = 0; j < 4; j++) {
        int p = p0 + wp + j * 16 + col;
        float v = acc[i][j][r] + bs;
        size_t off = (size_t)z * outZ + (size_t)m * PP + p;
        if (resid) v += resid[(size_t)z * residZ + (size_t)m * PP + p];
        if (OutF) OutF[off] = v;
        else OutH[off] = (f16)v;
      }
    }
  }
}

// qk GEMM: epilogue l2-normalizes groups of 32 consecutive p (per m row), stores fp16
__global__ __launch_bounds__(256) void k_mf_qk(const float* __restrict__ W,
                                               const f16* __restrict__ In, size_t inZ,
                                               f16* __restrict__ qkO, int K) {
  __shared__ f16 As[128][40];
  __shared__ f16 Bs[128][40];
  const f16* inB = In + (size_t)blockIdx.z * inZ;
  MF_STAGE
#pragma unroll
  for (int i = 0; i < 4; i++) {
    int mb = m0 + wm + i * 16 + quad * 4;
#pragma unroll
    for (int r = 0; r < 4; r++) {
      int m = mb + r;
      size_t base = (size_t)z * 512 * PP + (size_t)m * PP;
#pragma unroll
      for (int jp = 0; jp < 2; jp++) {
        float a0 = acc[i][2 * jp][r], a1 = acc[i][2 * jp + 1][r];
        float ss = a0 * a0 + a1 * a1;
        ss += __shfl_xor(ss, 1);
        ss += __shfl_xor(ss, 2);
        ss += __shfl_xor(ss, 4);
        ss += __shfl_xor(ss, 8);
        float inv = 1.0f / fmaxf(sqrtf(ss), 1e-12f);
        int pa = p0 + wp + 2 * jp * 16 + col;
        qkO[base + pa] = (f16)(a0 * inv);
        qkO[base + pa + 16] = (f16)(a1 * inv);
      }
    }
  }
}

// ---------------- q_probe + sh scores ----------------
__global__ __launch_bounds__(256) void k_probe(const __half* __restrict__ qk,
                                               float* __restrict__ qprobe,
                                               float* __restrict__ sh) {
  __shared__ float part[8][32];
  __shared__ float qp[32];
  int bh = blockIdx.x, b = bh >> 3, hd = bh & 7;
  int t = threadIdx.x, w = t & 31, pt = t >> 5;
  const __half* qb = qk + ((size_t)(b * 512 + hd * 32)) * PP;
  float s = 0.f;
  for (int d = 0; d < 32; d++) {
    const __half* qd = qb + (size_t)d * PP + w;
    for (int h = pt * 32; h < pt * 32 + 32; h++) s += __half2float(qd[h * 32]);
  }
  part[pt][w] = s;
  __syncthreads();
  if (t < 32) {
    float acc = 0.f;
    for (int i = 0; i < 8; i++) acc += part[i][w];
    qp[w] = acc;
    qprobe[bh * 32 + w] = acc;
  }
  __syncthreads();
  const __half* kb = qk + ((size_t)(b * 512 + 256 + hd * 32)) * PP;
  for (int dd = 0; dd < 4; dd++) {
    int d = pt * 4 + dd;
    const __half* kd = kb + (size_t)d * PP + w;
    float ks = 0.f;
    for (int h = 0; h < 256; h++) ks += __half2float(kd[h * 32]);
    float prod = qp[w] * ks;
#pragma unroll
    for (int off = 16; off; off >>= 1) prod += __shfl_xor(prod, off);
    if (w == 0) sh[bh * 32 + d] = prod;
  }
}

__global__ __launch_bounds__(64) void k_topk_h(const float* __restrict__ sh, int* __restrict__ ih) {
  int bh = blockIdx.x;
  if (threadIdx.x != 0) return;
  float v[32];
#pragma unroll
  for (int i = 0; i < 32; i++) v[i] = sh[bh * 32 + i];
  for (int s = 0; s < 8; s++) {
    int bi = 0; float bv = v[0];
#pragma unroll
    for (int i = 1; i < 32; i++) { if (v[i] > bv) { bv = v[i]; bi = i; } }
    ih[bh * 8 + s] = bi;
    v[bi] = -3.4e38f;
  }
}

__global__ __launch_bounds__(256) void k_sw_topk(const __half* __restrict__ qk,
                                                 const float* __restrict__ qprobe,
                                                 const int* __restrict__ ih,
                                                 int* __restrict__ iw) {
  __shared__ float qp[32];
  __shared__ float sw[256];
  __shared__ int ihs[8];
  int bh = blockIdx.x, b = bh >> 3, hd = bh & 7;
  int t = threadIdx.x;
  if (t < 32) qp[t] = qprobe[bh * 32 + t];
  if (t < 8) ihs[t] = ih[bh * 8 + t];
  __syncthreads();
  const __half* kb = qk + ((size_t)(b * 512 + 256 + hd * 32)) * PP;
  float s = 0.f;
  for (int a = 0; a < 8; a++) {
    const __half* kd = kb + (size_t)ihs[a] * PP + t * 32;
#pragma unroll
    for (int w = 0; w < 32; w++) s += qp[w] * __half2float(kd[w]);
  }
  sw[t] = s;
  __syncthreads();
  if (t == 0) {
    for (int sel = 0; sel < 8; sel++) {
      int bi = 0; float bv = sw[0];
      for (int i = 1; i < 256; i++) { if (sw[i] > bv) { bv = sw[i]; bi = i; } }
      iw[bh * 8 + sel] = bi;
      sw[bi] = -3.4e38f;
    }
  }
}

// ---------------- recompute v at the 64 selected positions per bh ----------------
__global__ __launch_bounds__(256) void k_vsel(const float* __restrict__ w_qkv,
                                              const float* __restrict__ x,
                                              const float* __restrict__ pm,
                                              const float* __restrict__ pr,
                                              const float* __restrict__ g,
                                              const float* __restrict__ bb,
                                              const int* __restrict__ ih,
                                              const int* __restrict__ iw,
                                              float* __restrict__ vsel) {
  __shared__ int ihs[8], iws[8];
  int bh = blockIdx.x, b = bh >> 3, hd = bh & 7;
  int t = threadIdx.x;
  if (t < 8) { ihs[t] = ih[bh * 8 + t]; iws[t] = iw[bh * 8 + t]; }
  __syncthreads();
  const float* xb = x + (size_t)b * CDIM * PP;
  for (int o = t; o < 2048; o += 256) {
    int j = o >> 5, w = o & 31;
    int d = ihs[j >> 3], hsp = iws[j & 7];
    int p = hsp * 32 + w;
    const float* wv = w_qkv + (size_t)(512 + hd * 32 + d) * 256;
    float pmv = pm[(size_t)b * PP + p], prv = pr[(size_t)b * PP + p];
    float s = 0.f;
    for (int c = 0; c < 256; c++)
      s += wv[c] * ((xb[(size_t)c * PP + p] - pmv) * prv * g[c] + bb[c]);
    vsel[((size_t)bh * 64 + j) * 32 + w] = s;
  }
}

// ---------------- attention, writes o_r fp16 ----------------
__global__ __launch_bounds__(256) void k_attn(const __half* __restrict__ qk,
                                              const float* __restrict__ vsel,
                                              const int* __restrict__ ih,
                                              const int* __restrict__ iw,
                                              f16* __restrict__ o_r) {
  __shared__ float ks[64][32];
  __shared__ float vs[64][32];
  __shared__ int ihs[8], iws[8];
  int bh = blockIdx.y, b = bh >> 3, hd = bh & 7;
  int t = threadIdx.x;
  if (t < 8) { ihs[t] = ih[bh * 8 + t]; iws[t] = iw[bh * 8 + t]; }
  __syncthreads();
  const __half* kb = qk + ((size_t)(b * 512 + 256 + hd * 32)) * PP;
  for (int idx = t; idx < 2048; idx += 256) {
    int j = idx >> 5, w = idx & 31;
    ks[j][w] = __half2float(kb[(size_t)ihs[j >> 3] * PP + iws[j & 7] * 32 + w]);
    vs[j][w] = vsel[((size_t)bh * 64 + j) * 32 + w];
  }
  __syncthreads();
  int i = blockIdx.x * 256 + t;
  int dq = i >> 8, hsp = i & 255;
  const __half* qrow = qk + ((size_t)(b * 512 + hd * 32 + dq)) * PP + hsp * 32;
  float q[32];
#pragma unroll
  for (int w = 0; w < 32; w++) q[w] = __half2float(qrow[w]);
  float mx = -3.4e38f;
  for (int j = 0; j < 64; j++) {
    float d = 0.f;
#pragma unroll
    for (int w = 0; w < 32; w++) d += q[w] * ks[j][w];
    mx = fmaxf(mx, d);
  }
  float o[32];
#pragma unroll
  for (int w = 0; w < 32; w++) o[w] = 0.f;
  float l = 0.f;
  for (int j = 0; j < 64; j++) {
    float d = 0.f;
#pragma unroll
    for (int w = 0; w < 32; w++) d += q[w] * ks[j][w];
    float e = __expf(d - mx);
    l += e;
#pragma unroll
    for (int w = 0; w < 32; w++) o[w] += e * vs[j][w];
  }
  float inv = 1.0f / l;
  f16* op = o_r + ((size_t)(b * 256 + hd * 32)) * PP + i;
#pragma unroll
  for (int dd = 0; dd < 32; dd++) op[(size_t)dd * PP] = (f16)(o[dd] * inv);
}

// ---------------- conv branch dw3x3 on x -> fp16 into channels [256,512) of bv512 ----------------
__global__ __launch_bounds__(256) void k_dw(const float* __restrict__ in,
                                            const float* __restrict__ wdw,
                                            const float* __restrict__ bdw,
                                            f16* __restrict__ out) {
  int bc = blockIdx.x;                 // b*256+c
  int b = bc >> 8, c = bc & 255;
  int p = blockIdx.y * 256 + threadIdx.x;
  int x0 = p >> 5, y0 = p & 31;
  const float* ip = in + (size_t)bc * PP;
  const float* wp = wdw + c * 9;
  float s = bdw[c];
#pragma unroll
  for (int i = 0; i < 3; i++) {
    int xx = x0 + i - 1;
    if (xx < 0 || xx >= HH) continue;
#pragma unroll
    for (int j = 0; j < 3; j++) {
      int yy = y0 + j - 1;
      if (yy < 0 || yy >= WW) continue;
      s += wp[i * 3 + j] * ip[xx * 32 + yy];
    }
  }
  out[((size_t)(b * 512 + 256 + c)) * PP + p] = (f16)s;
}

// ---------------- instance-norm stats, fp16 input ----------------
__global__ __launch_bounds__(256) void k_istats_h(const f16* __restrict__ in,
                                                  float* __restrict__ stm,
                                                  float* __restrict__ str) {
  __shared__ float ss[256], ss2[256];
  int row = blockIdx.x, t = threadIdx.x;
  const f16* p = in + (size_t)row * PP;
  float s = 0.f, s2 = 0.f;
  for (int i = t * 8; i < PP; i += 2048) {
    half8 v = *(const half8*)(p + i);
#pragma unroll
    for (int e = 0; e < 8; e++) { float f = (float)v[e]; s += f; s2 += f * f; }
  }
  ss[t] = s; ss2[t] = s2;
  __syncthreads();
  for (int off = 128; off; off >>= 1) {
    if (t < off) { ss[t] += ss[t + off]; ss2[t] += ss2[t + off]; }
    __syncthreads();
  }
  if (t == 0) {
    float m = ss[0] * (1.0f / PP);
    float var = ss2[0] * (1.0f / PP) - m * m;
    stm[row] = m;
    str[row] = rsqrtf(var + 1e-5f);
  }
}

// ---------------- gelu(inorm(.)) in place, fp16 ----------------
__global__ __launch_bounds__(256) void k_napply_h(f16* __restrict__ io,
                                                  const float* __restrict__ stm,
                                                  const float* __restrict__ str) {
  size_t idx8 = ((size_t)blockIdx.x * 256 + threadIdx.x) * 8;
  int row = (int)(idx8 >> 13);
  half8 v = *(half8*)(io + idx8);
  float m = stm[row], r = str[row];
#pragma unroll
  for (int e = 0; e < 8; e++) {
    float f = ((float)v[e] - m) * r;
    v[e] = (f16)(0.5f * f * (1.0f + erff(f * 0.70710678118f)));
  }
  *(half8*)(io + idx8) = v;
}

// ---------------- dw-conv stats on the fly from fp16 h1 ----------------
__global__ __launch_bounds__(256) void k_ffdw_stats_h(const f16* __restrict__ h1,
                                                      const float* __restrict__ wdw,
                                                      const float* __restrict__ bdw,
                                                      float* __restrict__ stm,
                                                      float* __restrict__ str) {
  __shared__ float ss[256], ss2[256];
  int c = blockIdx.x, zz = blockIdx.y;
  int row = zz * FFI + c;
  const f16* hp = h1 + (size_t)zz * FFI * PP + (size_t)c * PP;
  const float* wf = wdw + c * 9;
  float bd = bdw[c];
  int t = threadIdx.x;
  float s = 0.f, s2 = 0.f;
  for (int p = t; p < PP; p += 256) {
    int x0 = p >> 5, y0 = p & 31;
    float d = bd;
#pragma unroll
    for (int i = 0; i < 3; i++) {
      int xx = x0 + i - 1;
      if (xx < 0 || xx >= HH) continue;
#pragma unroll
      for (int j = 0; j < 3; j++) {
        int yy = y0 + j - 1;
        if (yy < 0 || yy >= WW) continue;
        d += wf[i * 3 + j] * (float)hp[xx * 32 + yy];
      }
    }
    s += d; s2 += d * d;
  }
  ss[t] = s; ss2[t] = s2;
  __syncthreads();
  for (int off = 128; off; off >>= 1) {
    if (t < off) { ss[t] += ss[t + off]; ss2[t] += ss2[t + off]; }
    __syncthreads();
  }
  if (t == 0) {
    float m = ss[0] * (1.0f / PP);
    float var = ss2[0] * (1.0f / PP) - m * m;
    stm[row] = m;
    str[row] = rsqrtf(var + 1e-5f);
  }
}

// ---------------- h2 = h1 + gelu(inorm(dwconv(h1))), fp16 ----------------
__global__ __launch_bounds__(256) void k_h2(const f16* __restrict__ h1,
                                            const float* __restrict__ wdw,
                                            const float* __restrict__ bdw,
                                            const float* __restrict__ stm,
                                            const float* __restrict__ str,
                                            f16* __restrict__ h2) {
  int c = blockIdx.x, pb = blockIdx.y, zz = blockIdx.z;
  int p = pb * 256 + threadIdx.x;
  int x0 = p >> 5, y0 = p & 31;
  const f16* hp = h1 + (size_t)zz * FFI * PP + (size_t)c * PP;
  const float* wf = wdw + c * 9;
  float d = bdw[c];
#pragma unroll
  for (int i = 0; i < 3; i++) {
    int xx = x0 + i - 1;
    if (xx < 0 || xx >= HH) continue;
#pragma unroll
    for (int j = 0; j < 3; j++) {
      int yy = y0 + j - 1;
      if (yy < 0 || yy >= WW) continue;
      d += wf[i * 3 + j] * (float)hp[xx * 32 + yy];
    }
  }
  int row = zz * FFI + c;
  float nv = (d - stm[row]) * str[row];
  float ge = 0.5f * nv * (1.0f + erff(nv * 0.70710678118f));
  h2[(size_t)zz * FFI * PP + (size_t)c * PP + p] = (f16)((float)hp[p] + ge);
}

// ---------------- fp32 inorm stats + apply (final) ----------------
__global__ __launch_bounds__(256) void k_istats(const float* __restrict__ in,
                                                float* __restrict__ stm,
                                                float* __restrict__ str) {
  __shared__ float ss[256], ss2[256];
  int row = blockIdx.x, t = threadIdx.x;
  const float* p = in + (size_t)row * PP;
  float s = 0.f, s2 = 0.f;
  for (int i = t; i < PP; i += 256) { float v = p[i]; s += v; s2 += v * v; }
  ss[t] = s; ss2[t] = s2;
  __syncthreads();
  for (int off = 128; off; off >>= 1) {
    if (t < off) { ss[t] += ss[t + off]; ss2[t] += ss2[t + off]; }
    __syncthreads();
  }
  if (t == 0) {
    float m = ss[0] * (1.0f / PP);
    float var = ss2[0] * (1.0f / PP) - m * m;
    stm[row] = m;
    str[row] = rsqrtf(var + 1e-5f);
  }
}

__global__ __launch_bounds__(256) void k_napply(float* __restrict__ io,
                                                const float* __restrict__ stm,
                                                const float* __restrict__ str) {
  size_t idx = (size_t)blockIdx.x * 256 + threadIdx.x;
  int row = (int)(idx >> 13);
  io[idx] = (io[idx] - stm[row]) * str[row];
}

extern "C" void kernel_launch(void* const* d_in, const int* in_sizes, int n_in,
                              void* d_out, int out_size, void* d_ws, size_t ws_size,
                              hipStream_t stream) {
  const float* x      = (const float*)d_in[0];
  const float* cln_g  = (const float*)d_in[1];
  const float* cln_b  = (const float*)d_in[2];
  const float* w_qkv  = (const float*)d_in[3];
  const float* w_out  = (const float*)d_in[4];
  const float* b_out  = (const float*)d_in[5];
  const float* w_dw   = (const float*)d_in[6];
  const float* b_dw   = (const float*)d_in[7];
  const float* w_comb = (const float*)d_in[8];
  const float* b_comb = (const float*)d_in[9];
  const float* w_ff1  = (const float*)d_in[10];
  const float* b_ff1  = (const float*)d_in[11];
  const float* w_ffdw = (const float*)d_in[12];
  const float* b_ffdw = (const float*)d_in[13];
  const float* w_ff2  = (const float*)d_in[14];
  const float* b_ff2  = (const float*)d_in[15];
  float* outF = (float*)d_out;

  float* ws = (float*)d_ws;
  f16* qk    = (f16*)ws;                  // 64MiB
  f16* bv512 = (f16*)ws;                  // after qk dead
  f16* h1    = (f16*)ws;                  // pair slab (2,1024,PP) = 32MiB
  f16* h2    = (f16*)ws + 16777216;       // pair slab at +32MiB
  f16* xn    = (f16*)d_out;               // 32MiB scratch in d_out
  f16* o_r   = (f16*)d_out;               // after xn dead
  f16* combT = (f16*)d_out;               // after o_r dead
  float* pm     = ws + OFF_PM;
  float* pr     = ws + OFF_PR;
  float* qprobe = ws + OFF_QPROBE;
  float* sh     = ws + OFF_SH;
  int*   ih     = (int*)(ws + OFF_IH);
  int*   iw     = (int*)(ws + OFF_IW);
  float* stm    = ws + OFF_STM;
  float* str    = ws + OFF_STR;
  float* vsel   = ws + OFF_VSEL;

  // 1. LN stats + xn fp16
  hipLaunchKernelGGL(k_lnstats, dim3(256), dim3(256), 0, stream, x, pm, pr);
  hipLaunchKernelGGL(k_ln_xnf16, dim3(8192), dim3(256), 0, stream, x, pm, pr, cln_g, cln_b, xn);
  // 2. q,k MFMA GEMM with fused l2norm -> qk fp16 (ws)
  hipLaunchKernelGGL(k_mf_qk, dim3(64, 4, 8), dim3(256), 0, stream,
                     w_qkv, xn, (size_t)CDIM * PP, qk, 256);
  // 3. probes + top-k + vsel
  hipLaunchKernelGGL(k_probe, dim3(64), dim3(256), 0, stream, (const __half*)qk, qprobe, sh);
  hipLaunchKernelGGL(k_topk_h, dim3(64), dim3(64), 0, stream, sh, ih);
  hipLaunchKernelGGL(k_sw_topk, dim3(64), dim3(256), 0, stream, (const __half*)qk, qprobe, ih, iw);
  hipLaunchKernelGGL(k_vsel, dim3(64), dim3(256), 0, stream,
                     w_qkv, x, pm, pr, cln_g, cln_b, ih, iw, vsel);
  // 4. attention -> o_r fp16 (d_out; xn dead)
  hipLaunchKernelGGL(k_attn, dim3(32, 64), dim3(256), 0, stream,
                     (const __half*)qk, vsel, ih, iw, o_r);
  // 5. attn_branch GEMM -> bv512 channels [0,256)  (qk dead)
  hipLaunchKernelGGL(k_mf, dim3(64, 2, 8), dim3(256), 0, stream,
                     w_out, o_r, (size_t)CDIM * PP, bv512, (float*)nullptr, (size_t)512 * PP,
                     b_out, (const float*)nullptr, (size_t)0, 256);
  // 6. conv branch -> bv512 channels [256,512)
  hipLaunchKernelGGL(k_dw, dim3(2048, 32), dim3(256), 0, stream, x, w_dw, b_dw, bv512);
  // 7. comb GEMM (K=512, +x residual) -> comb fp16 (d_out; o_r dead)
  hipLaunchKernelGGL(k_mf, dim3(64, 2, 8), dim3(256), 0, stream,
                     w_comb, bv512, (size_t)512 * PP, combT, (float*)nullptr, (size_t)CDIM * PP,
                     b_comb, x, (size_t)CDIM * PP, 512);
  // 8. FF chain in batch-pairs, DESCENDING (makes comb-in-d_out aliasing safe)
  for (int b = 6; b >= 0; b -= 2) {
    hipLaunchKernelGGL(k_mf, dim3(64, 8, 2), dim3(256), 0, stream,
                       w_ff1, combT + (size_t)b * CDIM * PP, (size_t)CDIM * PP,
                       h1, (float*)nullptr, (size_t)FFI * PP, b_ff1,
                       (const float*)nullptr, (size_t)0, 256);
    hipLaunchKernelGGL(k_istats_h, dim3(2048), dim3(256), 0, stream, h1, stm, str);
    hipLaunchKernelGGL(k_napply_h, dim3(8192), dim3(256), 0, stream, h1, stm, str);
    hipLaunchKernelGGL(k_ffdw_stats_h, dim3(1024, 2), dim3(256), 0, stream,
                       h1, w_ffdw, b_ffdw, stm, str);
    hipLaunchKernelGGL(k_h2, dim3(1024, 32, 2), dim3(256), 0, stream,
                       h1, w_ffdw, b_ffdw, stm, str, h2);
    hipLaunchKernelGGL(k_mf, dim3(64, 2, 2), dim3(256), 0, stream,
                       w_ff2, h2, (size_t)FFI * PP,
                       (f16*)nullptr, outF + (size_t)b * CDIM * PP, (size_t)CDIM * PP,
                       b_ff2, (const float*)nullptr, (size_t)0, 1024);
  }
  // 9. final inorm in place on d_out
  hipLaunchKernelGGL(k_istats, dim3(2048), dim3(256), 0, stream, outF, stm, str);
  hipLaunchKernelGGL(k_napply, dim3(65536), dim3(256), 0, stream, outF, stm, str);
}

// Round 5
// 1480.852 us; speedup vs baseline: 2.4178x; 1.1614x over previous
//
#include <hip/hip_runtime.h>
#include <hip/hip_fp16.h>
#include <math.h>

#define B_    8
#define CDIM  256
#define HH    256
#define WW    32
#define PP    8192
#define HEADS 8
#define FFI   1024

typedef _Float16 f16;
typedef _Float16 half8 __attribute__((ext_vector_type(8)));
typedef _Float16 half4 __attribute__((ext_vector_type(4)));
typedef _Float16 f16x2v __attribute__((ext_vector_type(2)));
typedef float f32x4 __attribute__((ext_vector_type(4)));

// ---------------- workspace layout (float offsets) ----------------
// BIG [0,16777216): qk f16 (8,512,8192) -> bv512 f16 -> h1/h2 pair slabs
static const size_t OFF_QPROBE = 16908288;
static const size_t OFF_SH     = 16910336;
static const size_t OFF_IH     = 16912384;
static const size_t OFF_IW     = 16912896;
static const size_t OFF_STM    = 16913408;
static const size_t OFF_STR    = 16921600;
static const size_t OFF_VSEL   = 16929792;
static const size_t OFF_W16    = 17060864;   // 917504 halves = 458752 floats
// end: 17519616 floats (~66.9 MiB)

// fp16 weight region offsets (in halves)
#define WH_QKV  0
#define WH_OUT  196608
#define WH_COMB 262144
#define WH_FF1  393216
#define WH_FF2  655360

// ---------------- weights -> fp16 (every launch; ws re-poisoned) ----------------
__global__ __launch_bounds__(256) void k_wcvt(const float* __restrict__ s0,
                                              const float* __restrict__ s1,
                                              const float* __restrict__ s2,
                                              const float* __restrict__ s3,
                                              const float* __restrict__ s4,
                                              f16* __restrict__ dst) {
  int blk = blockIdx.x;   // 896 blocks x 1024 elems
  const float* src; size_t base;
  if (blk < 192)      { src = s0; base = WH_QKV;  }
  else if (blk < 256) { src = s1; base = WH_OUT;  blk -= 192; }
  else if (blk < 384) { src = s2; base = WH_COMB; blk -= 256; }
  else if (blk < 640) { src = s3; base = WH_FF1;  blk -= 384; }
  else                { src = s4; base = WH_FF2;  blk -= 640; }
  int off = blk * 1024 + threadIdx.x * 4;
  float4 v = *(const float4*)(src + off);
  half4 h; h[0] = (f16)v.x; h[1] = (f16)v.y; h[2] = (f16)v.z; h[3] = (f16)v.w;
  *(half4*)(dst + base + off) = h;
}

// ---------------- fused channel-LN -> xn fp16 ----------------
__global__ __launch_bounds__(256) void k_lnxn(const float* __restrict__ x,
                                              const float* __restrict__ g,
                                              const float* __restrict__ bb,
                                              f16* __restrict__ xn) {
  int idx = blockIdx.x * 256 + threadIdx.x;      // 65536 = b*PP + p
  int b = idx >> 13, p = idx & 8191;
  const float* xp = x + (size_t)b * CDIM * PP + p;
  float s = 0.f, s2 = 0.f;
  for (int c = 0; c < CDIM; c++) { float v = xp[(size_t)c * PP]; s += v; s2 += v * v; }
  float m = s * (1.0f / CDIM);
  float var = s2 * (1.0f / CDIM) - m * m;
  float r = rsqrtf(var + 1e-5f);
  f16* xo = xn + (size_t)b * CDIM * PP + p;
  for (int c = 0; c < CDIM; c++)
    xo[(size_t)c * PP] = (f16)((xp[(size_t)c * PP] - m) * r * g[c] + bb[c]);
}

// ================= MFMA fp16 GEMM (128x128 tile, BK=32), fp16 weights =================
#define MF_STAGE                                                                   \
  int t = threadIdx.x;                                                             \
  int p0 = blockIdx.x * 128, m0 = blockIdx.y * 128, z = blockIdx.z;                \
  int lane = t & 63, wave = t >> 6;                                                \
  int wm = (wave >> 1) * 64, wp = (wave & 1) * 64;                                 \
  int col = lane & 15, quad = lane >> 4;                                           \
  f32x4 acc[4][4];                                                                 \
  _Pragma("unroll") for (int i = 0; i < 4; i++)                                    \
  _Pragma("unroll") for (int j = 0; j < 4; j++)                                    \
      acc[i][j] = (f32x4){0.f, 0.f, 0.f, 0.f};                                     \
  int am = t >> 1, ak = (t & 1) * 16;                                              \
  int bp = (t & 15) * 8, bk = (t >> 4) * 2;                                        \
  int erot = t & 7;                                                                \
  for (int k0 = 0; k0 < K; k0 += 32) {                                             \
    const f16* wr = W + (size_t)(m0 + am) * K + k0 + ak;                           \
    half8 w0 = *(const half8*)wr;                                                  \
    half8 w1 = *(const half8*)(wr + 8);                                            \
    *(half8*)&As[am][ak] = w0;                                                     \
    *(half8*)&As[am][ak + 8] = w1;                                                 \
    half8 r0 = *(const half8*)(inB + (size_t)(k0 + bk) * PP + p0 + bp);            \
    half8 r1 = *(const half8*)(inB + (size_t)(k0 + bk + 1) * PP + p0 + bp);        \
    _Pragma("unroll") for (int e0 = 0; e0 < 8; e0++) {                             \
      int e = (e0 + erot) & 7;                                                     \
      f16x2v pr2; pr2[0] = r0[e]; pr2[1] = r1[e];                                  \
      *(f16x2v*)&Bs[bp + e][bk] = pr2;                                             \
    }                                                                              \
    __syncthreads();                                                               \
    half8 af[4], bf[4];                                                            \
    _Pragma("unroll") for (int i = 0; i < 4; i++)                                  \
      af[i] = *(const half8*)&As[wm + i * 16 + col][quad * 8];                     \
    _Pragma("unroll") for (int j = 0; j < 4; j++)                                  \
      bf[j] = *(const half8*)&Bs[wp + j * 16 + col][quad * 8];                     \
    _Pragma("unroll") for (int i = 0; i < 4; i++)                                  \
    _Pragma("unroll") for (int j = 0; j < 4; j++)                                  \
        acc[i][j] = __builtin_amdgcn_mfma_f32_16x16x32_f16(af[i], bf[j],           \
                                                           acc[i][j], 0, 0, 0);    \
    __syncthreads();                                                               \
  }

__global__ __launch_bounds__(256) void k_mf(const f16* __restrict__ W,
                                            const f16* __restrict__ In, size_t inZ,
                                            f16* __restrict__ OutH,
                                            float* __restrict__ OutF, size_t outZ,
                                            const float* __restrict__ bias,
                                            const float* __restrict__ resid, size_t residZ,
                                            int K) {
  __shared__ f16 As[128][40];
  __shared__ f16 Bs[128][40];
  const f16* inB = In + (size_t)blockIdx.z * inZ;
  MF_STAGE
#pragma unroll
  for (int i = 0; i < 4; i++) {
    int mb = m0 + wm + i * 16 + quad * 4;
#pragma unroll
    for (int r = 0; r < 4; r++) {
      int m = mb + r;
      float bs = bias ? bias[m] : 0.f;
#pragma unroll
      for (int j = 0; j < 4; j++) {
        int p = p0 + wp + j * 16 + col;
        float v = acc[i][j][r] + bs;
        size_t off = (size_t)z * outZ + (size_t)m * PP + p;
        if (resid) v += resid[(size_t)z * residZ + (size_t)m * PP + p];
        if (OutF) OutF[off] = v;
        else OutH[off] = (f16)v;
      }
    }
  }
}

// qk GEMM: epilogue l2-normalizes groups of 32 consecutive p, stores fp16
__global__ __launch_bounds__(256) void k_mf_qk(const f16* __restrict__ W,
                                               const f16* __restrict__ In, size_t inZ,
                                               f16* __restrict__ qkO, int K) {
  __shared__ f16 As[128][40];
  __shared__ f16 Bs[128][40];
  const f16* inB = In + (size_t)blockIdx.z * inZ;
  MF_STAGE
#pragma unroll
  for (int i = 0; i < 4; i++) {
    int mb = m0 + wm + i * 16 + quad * 4;
#pragma unroll
    for (int r = 0; r < 4; r++) {
      int m = mb + r;
      size_t base = (size_t)z * 512 * PP + (size_t)m * PP;
#pragma unroll
      for (int jp = 0; jp < 2; jp++) {
        float a0 = acc[i][2 * jp][r], a1 = acc[i][2 * jp + 1][r];
        float ss = a0 * a0 + a1 * a1;
        ss += __shfl_xor(ss, 1);
        ss += __shfl_xor(ss, 2);
        ss += __shfl_xor(ss, 4);
        ss += __shfl_xor(ss, 8);
        float inv = 1.0f / fmaxf(sqrtf(ss), 1e-12f);
        int pa = p0 + wp + 2 * jp * 16 + col;
        qkO[base + pa] = (f16)(a0 * inv);
        qkO[base + pa + 16] = (f16)(a1 * inv);
      }
    }
  }
}

// ---------------- q_probe + sh scores (vectorized) ----------------
__global__ __launch_bounds__(256) void k_probe(const f16* __restrict__ qk,
                                               float* __restrict__ qprobe,
                                               float* __restrict__ sh) {
  __shared__ float red[64][32];
  __shared__ float qp[32];
  __shared__ float ksum[32][32];
  int bh = blockIdx.x, b = bh >> 3, hd = bh & 7;
  int t = threadIdx.x;
  const f16* qb = qk + ((size_t)(b * 512 + hd * 32)) * PP;
  // phase 1: qp[w] = sum over (d,h) of q[d][h][w]
  {
    int g = t >> 2, wq = (t & 3) * 8;
    float s[8];
#pragma unroll
    for (int e = 0; e < 8; e++) s[e] = 0.f;
    for (int it = 0; it < 128; it++) {
      int row = g * 128 + it;
      half8 v = *(const half8*)(qb + (size_t)(row >> 8) * PP + (row & 255) * 32 + wq);
#pragma unroll
      for (int e = 0; e < 8; e++) s[e] += (float)v[e];
    }
#pragma unroll
    for (int e = 0; e < 8; e++) red[g][wq + e] = s[e];
  }
  __syncthreads();
  if (t < 32) {
    float a = 0.f;
    for (int g = 0; g < 64; g++) a += red[g][t];
    qp[t] = a;
    qprobe[bh * 32 + t] = a;
  }
  // phase 2: ksum[d][w] = sum over h of k[d][h][w]
  const f16* kb = qk + ((size_t)(b * 512 + 256 + hd * 32)) * PP;
  {
    int d = t >> 3, wq = (t & 7) * 4;
    float s[4] = {0.f, 0.f, 0.f, 0.f};
    for (int h = 0; h < 256; h++) {
      half4 v = *(const half4*)(kb + (size_t)d * PP + h * 32 + wq);
#pragma unroll
      for (int e = 0; e < 4; e++) s[e] += (float)v[e];
    }
#pragma unroll
    for (int e = 0; e < 4; e++) ksum[d][wq + e] = s[e];
  }
  __syncthreads();
  if (t < 32) {
    float a = 0.f;
    for (int w = 0; w < 32; w++) a += qp[w] * ksum[t][w];
    sh[bh * 32 + t] = a;
  }
}

__global__ __launch_bounds__(64) void k_topk_h(const float* __restrict__ sh, int* __restrict__ ih) {
  int bh = blockIdx.x;
  if (threadIdx.x != 0) return;
  float v[32];
#pragma unroll
  for (int i = 0; i < 32; i++) v[i] = sh[bh * 32 + i];
  for (int s = 0; s < 8; s++) {
    int bi = 0; float bv = v[0];
#pragma unroll
    for (int i = 1; i < 32; i++) { if (v[i] > bv) { bv = v[i]; bi = i; } }
    ih[bh * 8 + s] = bi;
    v[bi] = -3.4e38f;
  }
}

__global__ __launch_bounds__(256) void k_sw_topk(const f16* __restrict__ qk,
                                                 const float* __restrict__ qprobe,
                                                 const int* __restrict__ ih,
                                                 int* __restrict__ iw) {
  __shared__ float qp[32];
  __shared__ float sw[256];
  __shared__ int ihs[8];
  int bh = blockIdx.x, b = bh >> 3, hd = bh & 7;
  int t = threadIdx.x;
  if (t < 32) qp[t] = qprobe[bh * 32 + t];
  if (t < 8) ihs[t] = ih[bh * 8 + t];
  __syncthreads();
  const f16* kb = qk + ((size_t)(b * 512 + 256 + hd * 32)) * PP;
  float s = 0.f;
  for (int a = 0; a < 8; a++) {
    const f16* kd = kb + (size_t)ihs[a] * PP + t * 32;
#pragma unroll
    for (int w = 0; w < 32; w++) s += qp[w] * (float)kd[w];
  }
  sw[t] = s;
  __syncthreads();
  if (t == 0) {
    for (int sel = 0; sel < 8; sel++) {
      int bi = 0; float bv = sw[0];
      for (int i = 1; i < 256; i++) { if (sw[i] > bv) { bv = sw[i]; bi = i; } }
      iw[bh * 8 + sel] = bi;
      sw[bi] = -3.4e38f;
    }
  }
}

// ---------------- v at selected positions, LDS-staged from xn fp16 ----------------
__global__ __launch_bounds__(256) void k_vsel2(const f16* __restrict__ xn,
                                               const f16* __restrict__ W16,
                                               const int* __restrict__ ih,
                                               const int* __restrict__ iw,
                                               float* __restrict__ vsel) {
  __shared__ f16 xg[64][264];
  __shared__ float wrow[8][64];
  __shared__ int ihs[8], iws8[8];
  int bh = blockIdx.x, b = bh >> 3, hd = bh & 7;
  int t = threadIdx.x;
  if (t < 8) { ihs[t] = ih[bh * 8 + t]; iws8[t] = iw[bh * 8 + t]; }
  __syncthreads();
  float acc[8];
#pragma unroll
  for (int a = 0; a < 8; a++) acc[a] = 0.f;
  for (int c0 = 0; c0 < 256; c0 += 64) {
    // stage xg[cc][n] = xn[c0+cc][iws8[n>>5]*32 + (n&31)]
    for (int rep = 0; rep < 2; rep++) {
      int cc = rep * 32 + (t >> 3);
      int seg = t & 7;
#pragma unroll
      for (int u = 0; u < 4; u++) {
        int h8 = seg * 4 + u;                 // 0..31
        int bi = h8 >> 2, wq = (h8 & 3) * 8;
        half8 v = *(const half8*)(xn + ((size_t)(b * 256 + c0 + cc)) * PP + iws8[bi] * 32 + wq);
        *(half8*)&xg[cc][h8 * 8] = v;
      }
    }
    // stage wrow[a][cc]
    for (int rep = 0; rep < 2; rep++) {
      int idx = t + rep * 256;
      int a = idx >> 6, cc = idx & 63;
      wrow[a][cc] = (float)W16[(size_t)(512 + hd * 32 + ihs[a]) * 256 + c0 + cc];
    }
    __syncthreads();
    for (int cc = 0; cc < 64; cc++) {
      float xv = (float)xg[cc][t];
#pragma unroll
      for (int a = 0; a < 8; a++) acc[a] += wrow[a][cc] * xv;
    }
    __syncthreads();
  }
  int bi = t >> 5, w = t & 31;
#pragma unroll
  for (int a = 0; a < 8; a++)
    vsel[((size_t)bh * 64 + a * 8 + bi) * 32 + w] = acc[a];
}

// ---------------- MFMA attention ----------------
__global__ __launch_bounds__(256) void k_attn_mf(const f16* __restrict__ qk,
                                                 const float* __restrict__ vsel,
                                                 const int* __restrict__ ih,
                                                 const int* __restrict__ iw,
                                                 f16* __restrict__ o_r) {
  __shared__ f16 Ks[64][40];
  __shared__ f16 Vt[32][72];
  __shared__ f16 Ps[4][32][72];
  __shared__ f16 Os[32][136];
  __shared__ int ihs[8], iws8[8];
  int bh = blockIdx.y, b = bh >> 3, hd = bh & 7;
  int t = threadIdx.x;
  if (t < 8) { ihs[t] = ih[bh * 8 + t]; iws8[t] = iw[bh * 8 + t]; }
  __syncthreads();
  // stage K_sel [j][w]
  {
    int j = t >> 2, wc = (t & 3) * 8;
    const f16* kb = qk + ((size_t)(b * 512 + 256 + hd * 32 + ihs[j >> 3])) * PP
                    + iws8[j & 7] * 32 + wc;
    *(half8*)&Ks[j][wc] = *(const half8*)kb;
  }
  // stage V transposed [w][j]
  for (int rep = 0; rep < 2; rep++) {
    int idx = t + rep * 256;
    int j = idx >> 3, w4 = (idx & 7) * 4;
    float4 v = *(const float4*)(vsel + ((size_t)bh * 64 + j) * 32 + w4);
    Vt[w4 + 0][j] = (f16)v.x; Vt[w4 + 1][j] = (f16)v.y;
    Vt[w4 + 2][j] = (f16)v.z; Vt[w4 + 3][j] = (f16)v.w;
  }
  __syncthreads();
  int wv = t >> 6, lane = t & 63, col = lane & 15, quad = lane >> 4;
  int i0 = blockIdx.x * 128;
  int dq = i0 >> 8;
  int hb = (i0 & 255) + wv * 32;
  const f16* qbase = qk + ((size_t)(b * 512 + hd * 32 + dq)) * PP;
  // S = Q K^T  (2 m-tiles x 4 n-tiles per wave)
  f32x4 sacc[2][4];
#pragma unroll
  for (int i = 0; i < 2; i++)
#pragma unroll
    for (int j = 0; j < 4; j++) sacc[i][j] = (f32x4){0.f, 0.f, 0.f, 0.f};
#pragma unroll
  for (int mt = 0; mt < 2; mt++) {
    half8 af = *(const half8*)(qbase + (size_t)(hb + mt * 16 + col) * 32 + quad * 8);
#pragma unroll
    for (int nt = 0; nt < 4; nt++) {
      half8 bf = *(const half8*)&Ks[nt * 16 + col][quad * 8];
      sacc[mt][nt] = __builtin_amdgcn_mfma_f32_16x16x32_f16(af, bf, sacc[mt][nt], 0, 0, 0);
    }
  }
  // softmax per row (row = quad*4+r), cols across 16 lanes x 4 nt
#pragma unroll
  for (int mt = 0; mt < 2; mt++) {
#pragma unroll
    for (int r = 0; r < 4; r++) {
      float s0 = sacc[mt][0][r], s1 = sacc[mt][1][r], s2 = sacc[mt][2][r], s3 = sacc[mt][3][r];
      float mx = fmaxf(fmaxf(s0, s1), fmaxf(s2, s3));
      mx = fmaxf(mx, __shfl_xor(mx, 1));
      mx = fmaxf(mx, __shfl_xor(mx, 2));
      mx = fmaxf(mx, __shfl_xor(mx, 4));
      mx = fmaxf(mx, __shfl_xor(mx, 8));
      float e0 = __expf(s0 - mx), e1 = __expf(s1 - mx), e2 = __expf(s2 - mx), e3 = __expf(s3 - mx);
      float l = e0 + e1 + e2 + e3;
      l += __shfl_xor(l, 1);
      l += __shfl_xor(l, 2);
      l += __shfl_xor(l, 4);
      l += __shfl_xor(l, 8);
      float inv = 1.0f / l;
      int row = mt * 16 + quad * 4 + r;
      Ps[wv][row][0 * 16 + col] = (f16)(e0 * inv);
      Ps[wv][row][1 * 16 + col] = (f16)(e1 * inv);
      Ps[wv][row][2 * 16 + col] = (f16)(e2 * inv);
      Ps[wv][row][3 * 16 + col] = (f16)(e3 * inv);
    }
  }
  __syncthreads();
  // O = P V  (K=64 -> 2 chained MFMAs)
  f32x4 oacc[2][2];
#pragma unroll
  for (int i = 0; i < 2; i++)
#pragma unroll
    for (int j = 0; j < 2; j++) oacc[i][j] = (f32x4){0.f, 0.f, 0.f, 0.f};
#pragma unroll
  for (int kk = 0; kk < 2; kk++) {
    half8 ap[2], bv[2];
#pragma unroll
    for (int mt = 0; mt < 2; mt++) ap[mt] = *(const half8*)&Ps[wv][mt * 16 + col][kk * 32 + quad * 8];
#pragma unroll
    for (int wn = 0; wn < 2; wn++) bv[wn] = *(const half8*)&Vt[wn * 16 + col][kk * 32 + quad * 8];
#pragma unroll
    for (int mt = 0; mt < 2; mt++)
#pragma unroll
      for (int wn = 0; wn < 2; wn++)
        oacc[mt][wn] = __builtin_amdgcn_mfma_f32_16x16x32_f16(ap[mt], bv[wn], oacc[mt][wn], 0, 0, 0);
  }
#pragma unroll
  for (int mt = 0; mt < 2; mt++)
#pragma unroll
    for (int wn = 0; wn < 2; wn++)
#pragma unroll
      for (int r = 0; r < 4; r++)
        Os[wn * 16 + col][wv * 32 + mt * 16 + quad * 4 + r] = (f16)oacc[mt][wn][r];
  __syncthreads();
  // coalesced write: o_r[(b*256+hd*32+dd)*PP + i0 + io]
  {
    int dd = t >> 3, seg = t & 7;
#pragma unroll
    for (int u = 0; u < 2; u++) {
      int io = (seg * 2 + u) * 8;
      *(half8*)(o_r + ((size_t)(b * 256 + hd * 32 + dd)) * PP + i0 + io) = *(const half8*)&Os[dd][io];
    }
  }
}

// ---------------- conv branch dw3x3 on x -> fp16 channels [256,512) of bv512 ----------------
__global__ __launch_bounds__(256) void k_dw(const float* __restrict__ in,
                                            const float* __restrict__ wdw,
                                            const float* __restrict__ bdw,
                                            f16* __restrict__ out) {
  int bc = blockIdx.x;
  int b = bc >> 8, c = bc & 255;
  int p = blockIdx.y * 256 + threadIdx.x;
  int x0 = p >> 5, y0 = p & 31;
  const float* ip = in + (size_t)bc * PP;
  const float* wp = wdw + c * 9;
  float s = bdw[c];
#pragma unroll
  for (int i = 0; i < 3; i++) {
    int xx = x0 + i - 1;
    if (xx < 0 || xx >= HH) continue;
#pragma unroll
    for (int j = 0; j < 3; j++) {
      int yy = y0 + j - 1;
      if (yy < 0 || yy >= WW) continue;
      s += wp[i * 3 + j] * ip[xx * 32 + yy];
    }
  }
  out[((size_t)(b * 512 + 256 + c)) * PP + p] = (f16)s;
}

// ---------------- instance-norm stats (fp16 input) ----------------
__global__ __launch_bounds__(256) void k_istats_h(const f16* __restrict__ in,
                                                  float* __restrict__ stm,
                                                  float* __restrict__ str) {
  __shared__ float ss[256], ss2[256];
  int row = blockIdx.x, t = threadIdx.x;
  const f16* p = in + (size_t)row * PP;
  float s = 0.f, s2 = 0.f;
  for (int i = t * 8; i < PP; i += 2048) {
    half8 v = *(const half8*)(p + i);
#pragma unroll
    for (int e = 0; e < 8; e++) { float f = (float)v[e]; s += f; s2 += f * f; }
  }
  ss[t] = s; ss2[t] = s2;
  __syncthreads();
  for (int off = 128; off; off >>= 1) {
    if (t < off) { ss[t] += ss[t + off]; ss2[t] += ss2[t + off]; }
    __syncthreads();
  }
  if (t == 0) {
    float m = ss[0] * (1.0f / PP);
    float var = ss2[0] * (1.0f / PP) - m * m;
    stm[row] = m;
    str[row] = rsqrtf(var + 1e-5f);
  }
}

// ---------------- gelu(inorm(.)) in place, fp16 ----------------
__global__ __launch_bounds__(256) void k_napply_h(f16* __restrict__ io,
                                                  const float* __restrict__ stm,
                                                  const float* __restrict__ str) {
  size_t idx8 = ((size_t)blockIdx.x * 256 + threadIdx.x) * 8;
  int row = (int)(idx8 >> 13);
  half8 v = *(half8*)(io + idx8);
  float m = stm[row], r = str[row];
#pragma unroll
  for (int e = 0; e < 8; e++) {
    float f = ((float)v[e] - m) * r;
    v[e] = (f16)(0.5f * f * (1.0f + erff(f * 0.70710678118f)));
  }
  *(half8*)(io + idx8) = v;
}

// ---------------- dw-conv stats on the fly from fp16 h1 ----------------
__global__ __launch_bounds__(256) void k_ffdw_stats_h(const f16* __restrict__ h1,
                                                      const float* __restrict__ wdw,
                                                      const float* __restrict__ bdw,
                                                      float* __restrict__ stm,
                                                      float* __restrict__ str) {
  __shared__ float ss[256], ss2[256];
  int c = blockIdx.x, zz = blockIdx.y;
  int row = zz * FFI + c;
  const f16* hp = h1 + (size_t)zz * FFI * PP + (size_t)c * PP;
  const float* wf = wdw + c * 9;
  float bd = bdw[c];
  int t = threadIdx.x;
  float s = 0.f, s2 = 0.f;
  for (int p = t; p < PP; p += 256) {
    int x0 = p >> 5, y0 = p & 31;
    float d = bd;
#pragma unroll
    for (int i = 0; i < 3; i++) {
      int xx = x0 + i - 1;
      if (xx < 0 || xx >= HH) continue;
#pragma unroll
      for (int j = 0; j < 3; j++) {
        int yy = y0 + j - 1;
        if (yy < 0 || yy >= WW) continue;
        d += wf[i * 3 + j] * (float)hp[xx * 32 + yy];
      }
    }
    s += d; s2 += d * d;
  }
  ss[t] = s; ss2[t] = s2;
  __syncthreads();
  for (int off = 128; off; off >>= 1) {
    if (t < off) { ss[t] += ss[t + off]; ss2[t] += ss2[t + off]; }
    __syncthreads();
  }
  if (t == 0) {
    float m = ss[0] * (1.0f / PP);
    float var = ss2[0] * (1.0f / PP) - m * m;
    stm[row] = m;
    str[row] = rsqrtf(var + 1e-5f);
  }
}

// ---------------- h2 = h1 + gelu(inorm(dwconv(h1))) ----------------
__global__ __launch_bounds__(256) void k_h2(const f16* __restrict__ h1,
                                            const float* __restrict__ wdw,
                                            const float* __restrict__ bdw,
                                            const float* __restrict__ stm,
                                            const float* __restrict__ str,
                                            f16* __restrict__ h2) {
  int c = blockIdx.x, pb = blockIdx.y, zz = blockIdx.z;
  int p = pb * 256 + threadIdx.x;
  int x0 = p >> 5, y0 = p & 31;
  const f16* hp = h1 + (size_t)zz * FFI * PP + (size_t)c * PP;
  const float* wf = wdw + c * 9;
  float d = bdw[c];
#pragma unroll
  for (int i = 0; i < 3; i++) {
    int xx = x0 + i - 1;
    if (xx < 0 || xx >= HH) continue;
#pragma unroll
    for (int j = 0; j < 3; j++) {
      int yy = y0 + j - 1;
      if (yy < 0 || yy >= WW) continue;
      d += wf[i * 3 + j] * (float)hp[xx * 32 + yy];
    }
  }
  int row = zz * FFI + c;
  float nv = (d - stm[row]) * str[row];
  float ge = 0.5f * nv * (1.0f + erff(nv * 0.70710678118f));
  h2[(size_t)zz * FFI * PP + (size_t)c * PP + p] = (f16)((float)hp[p] + ge);
}

// ---------------- fp32 inorm stats + apply (final) ----------------
__global__ __launch_bounds__(256) void k_istats(const float* __restrict__ in,
                                                float* __restrict__ stm,
                                                float* __restrict__ str) {
  __shared__ float ss[256], ss2[256];
  int row = blockIdx.x, t = threadIdx.x;
  const float* p = in + (size_t)row * PP;
  float s = 0.f, s2 = 0.f;
  for (int i = t; i < PP; i += 256) { float v = p[i]; s += v; s2 += v * v; }
  ss[t] = s; ss2[t] = s2;
  __syncthreads();
  for (int off = 128; off; off >>= 1) {
    if (t < off) { ss[t] += ss[t + off]; ss2[t] += ss2[t + off]; }
    __syncthreads();
  }
  if (t == 0) {
    float m = ss[0] * (1.0f / PP);
    float var = ss2[0] * (1.0f / PP) - m * m;
    stm[row] = m;
    str[row] = rsqrtf(var + 1e-5f);
  }
}

__global__ __launch_bounds__(256) void k_napply(float* __restrict__ io,
                                                const float* __restrict__ stm,
                                                const float* __restrict__ str) {
  size_t idx = (size_t)blockIdx.x * 256 + threadIdx.x;
  int row = (int)(idx >> 13);
  io[idx] = (io[idx] - stm[row]) * str[row];
}

extern "C" void kernel_launch(void* const* d_in, const int* in_sizes, int n_in,
                              void* d_out, int out_size, void* d_ws, size_t ws_size,
                              hipStream_t stream) {
  const float* x      = (const float*)d_in[0];
  const float* cln_g  = (const float*)d_in[1];
  const float* cln_b  = (const float*)d_in[2];
  const float* w_qkv  = (const float*)d_in[3];
  const float* w_out  = (const float*)d_in[4];
  const float* b_out  = (const float*)d_in[5];
  const float* w_dw   = (const float*)d_in[6];
  const float* b_dw   = (const float*)d_in[7];
  const float* w_comb = (const float*)d_in[8];
  const float* b_comb = (const float*)d_in[9];
  const float* w_ff1  = (const float*)d_in[10];
  const float* b_ff1  = (const float*)d_in[11];
  const float* w_ffdw = (const float*)d_in[12];
  const float* b_ffdw = (const float*)d_in[13];
  const float* w_ff2  = (const float*)d_in[14];
  const float* b_ff2  = (const float*)d_in[15];
  float* outF = (float*)d_out;

  float* ws = (float*)d_ws;
  f16* qk    = (f16*)ws;
  f16* bv512 = (f16*)ws;
  f16* h1    = (f16*)ws;
  f16* h2    = (f16*)ws + 16777216;
  f16* xn    = (f16*)d_out;
  f16* o_r   = (f16*)d_out;
  f16* combT = (f16*)d_out;
  float* qprobe = ws + OFF_QPROBE;
  float* sh     = ws + OFF_SH;
  int*   ih     = (int*)(ws + OFF_IH);
  int*   iw     = (int*)(ws + OFF_IW);
  float* stm    = ws + OFF_STM;
  float* str    = ws + OFF_STR;
  float* vsel   = ws + OFF_VSEL;
  f16*   W16    = (f16*)(ws + OFF_W16);

  // 0. weights -> fp16
  hipLaunchKernelGGL(k_wcvt, dim3(896), dim3(256), 0, stream,
                     w_qkv, w_out, w_comb, w_ff1, w_ff2, W16);
  // 1. fused channel-LN -> xn fp16 (d_out)
  hipLaunchKernelGGL(k_lnxn, dim3(256), dim3(256), 0, stream, x, cln_g, cln_b, xn);
  // 2. q,k GEMM (+l2norm) -> qk fp16 (ws)
  hipLaunchKernelGGL(k_mf_qk, dim3(64, 4, 8), dim3(256), 0, stream,
                     W16 + WH_QKV, xn, (size_t)CDIM * PP, qk, 256);
  // 3. probes + top-k
  hipLaunchKernelGGL(k_probe, dim3(64), dim3(256), 0, stream, qk, qprobe, sh);
  hipLaunchKernelGGL(k_topk_h, dim3(64), dim3(64), 0, stream, sh, ih);
  hipLaunchKernelGGL(k_sw_topk, dim3(64), dim3(256), 0, stream, qk, qprobe, ih, iw);
  // 4. v at selected positions (reads xn, still live)
  hipLaunchKernelGGL(k_vsel2, dim3(64), dim3(256), 0, stream, xn, W16 + WH_QKV, ih, iw, vsel);
  // 5. MFMA attention -> o_r fp16 (d_out; xn dead)
  hipLaunchKernelGGL(k_attn_mf, dim3(64, 64), dim3(256), 0, stream, qk, vsel, ih, iw, o_r);
  // 6. attn_branch GEMM -> bv512 [0,256) (qk dead)
  hipLaunchKernelGGL(k_mf, dim3(64, 2, 8), dim3(256), 0, stream,
                     W16 + WH_OUT, o_r, (size_t)CDIM * PP, bv512, (float*)nullptr, (size_t)512 * PP,
                     b_out, (const float*)nullptr, (size_t)0, 256);
  // 7. conv branch -> bv512 [256,512)
  hipLaunchKernelGGL(k_dw, dim3(2048, 32), dim3(256), 0, stream, x, w_dw, b_dw, bv512);
  // 8. comb GEMM (K=512, +x residual) -> combT fp16 (d_out; o_r dead)
  hipLaunchKernelGGL(k_mf, dim3(64, 2, 8), dim3(256), 0, stream,
                     W16 + WH_COMB, bv512, (size_t)512 * PP, combT, (float*)nullptr, (size_t)CDIM * PP,
                     b_comb, x, (size_t)CDIM * PP, 512);
  // 9. FF chain in batch-pairs, descending (comb-in-d_out aliasing safe)
  for (int b = 6; b >= 0; b -= 2) {
    hipLaunchKernelGGL(k_mf, dim3(64, 8, 2), dim3(256), 0, stream,
                       W16 + WH_FF1, combT + (size_t)b * CDIM * PP, (size_t)CDIM * PP,
                       h1, (float*)nullptr, (size_t)FFI * PP, b_ff1,
                       (const float*)nullptr, (size_t)0, 256);
    hipLaunchKernelGGL(k_istats_h, dim3(2048), dim3(256), 0, stream, h1, stm, str);
    hipLaunchKernelGGL(k_napply_h, dim3(8192), dim3(256), 0, stream, h1, stm, str);
    hipLaunchKernelGGL(k_ffdw_stats_h, dim3(1024, 2), dim3(256), 0, stream,
                       h1, w_ffdw, b_ffdw, stm, str);
    hipLaunchKernelGGL(k_h2, dim3(1024, 32, 2), dim3(256), 0, stream,
                       h1, w_ffdw, b_ffdw, stm, str, h2);
    hipLaunchKernelGGL(k_mf, dim3(64, 2, 2), dim3(256), 0, stream,
                       W16 + WH_FF2, h2, (size_t)FFI * PP,
                       (f16*)nullptr, outF + (size_t)b * CDIM * PP, (size_t)CDIM * PP,
                       b_ff2, (const float*)nullptr, (size_t)0, 1024);
  }
  // 10. final inorm in place on d_out
  hipLaunchKernelGGL(k_istats, dim3(2048), dim3(256), 0, stream, outF, stm, str);
  hipLaunchKernelGGL(k_napply, dim3(65536), dim3(256), 0, stream, outF, stm, str);
}